// Round 19
// baseline (74.593 us; speedup 1.0000x reference)
//
#include <hip/hip_runtime.h>
#include <stdint.h>

typedef unsigned short ushort_t;
typedef __attribute__((ext_vector_type(4))) float f32x4;
typedef __attribute__((ext_vector_type(8))) short short8;
typedef __attribute__((ext_vector_type(4))) ushort_t us4;
typedef __attribute__((ext_vector_type(4))) int i32x4;
typedef __attribute__((ext_vector_type(8))) int i32x8;

#define LDS_AS __attribute__((address_space(3)))
#define GLB_AS __attribute__((address_space(1)))

__device__ __forceinline__ ushort_t f2bf(float f) {
    uint32_t u = __float_as_uint(f);
    u += 0x7FFFu + ((u >> 16) & 1u);   // RNE
    return (ushort_t)(u >> 16);
}

__device__ __forceinline__ float bf2f(ushort_t u) {
    return __uint_as_float(((uint32_t)u) << 16);
}

__device__ __forceinline__ float dpp_shr1z(float x) {   // lane l <- lane l-1; lane 0 <- 0.0
    return __int_as_float(__builtin_amdgcn_update_dpp(
        0, __float_as_int(x), 0x138, 0xF, 0xF, false));  // wave_shr:1
}

// pack float4 -> 4 x fp8 e4m3 (OCP) in one uint32
__device__ __forceinline__ uint32_t pk_fp8(float4 x) {
    int u = __builtin_amdgcn_cvt_pk_fp8_f32(x.x, x.y, 0, false);   // bytes 0,1
    u = __builtin_amdgcn_cvt_pk_fp8_f32(x.z, x.w, u, true);        // bytes 2,3
    return (uint32_t)u;
}

// ---------- prep: row-normalize; frame/cand -> FP8 (A/B), video/sent/mean -> BF16 (Z) ----
__global__ __launch_bounds__(256) void k_prep_all(
    const float* __restrict__ frame, const float* __restrict__ cand,
    const float* __restrict__ video, const float* __restrict__ sent,
    uint8_t* __restrict__ A8, uint8_t* __restrict__ B8, ushort_t* __restrict__ Zbf,
    float* __restrict__ P)
{
    if (blockIdx.x == 0) {
        for (int i = threadIdx.x; i < 1152; i += 256) P[i] = 0.0f;
    }
    const int w = threadIdx.x >> 6, ln = threadIdx.x & 63;
    const int r = blockIdx.x * 4 + w;
    float4 x0, x1, x2;
    bool isfp8 = (r < 12288);
    uint8_t* dst8 = nullptr;
    ushort_t* dstz = nullptr;
    if (r < 8192) {
        const float4* s = (const float4*)(frame + (size_t)r * 768);
        x0 = s[ln]; x1 = s[ln + 64]; x2 = s[ln + 128];
        dst8 = A8 + (size_t)r * 768;
    } else if (r < 12288) {
        int q = r - 8192;
        const float4* s = (const float4*)(cand + (size_t)q * 768);
        x0 = s[ln]; x1 = s[ln + 64]; x2 = s[ln + 128];
        dst8 = B8 + (size_t)q * 768;
    } else if (r < 12416) {
        int q = r - 12288;
        const float4* s = (const float4*)(video + (size_t)q * 768);
        x0 = s[ln]; x1 = s[ln + 64]; x2 = s[ln + 128];
        dstz = Zbf + (size_t)q * 768;
    } else if (r < 12544) {
        int q = r - 12416;
        const float4* s = (const float4*)(sent + (size_t)q * 768);
        x0 = s[ln]; x1 = s[ln + 64]; x2 = s[ln + 128];
        dstz = Zbf + (size_t)(128 + q) * 768;
    } else {
        int b = r - 12544;
        x0 = x1 = x2 = make_float4(0.f, 0.f, 0.f, 0.f);
        for (int k = 0; k < 32; ++k) {
            const float4* s = (const float4*)(cand + (size_t)(b * 32 + k) * 768);
            float4 y0 = s[ln], y1 = s[ln + 64], y2 = s[ln + 128];
            x0.x += y0.x; x0.y += y0.y; x0.z += y0.z; x0.w += y0.w;
            x1.x += y1.x; x1.y += y1.y; x1.z += y1.z; x1.w += y1.w;
            x2.x += y2.x; x2.y += y2.y; x2.z += y2.z; x2.w += y2.w;
        }
        const float s32 = 1.0f / 32.0f;
        x0.x *= s32; x0.y *= s32; x0.z *= s32; x0.w *= s32;
        x1.x *= s32; x1.y *= s32; x1.z *= s32; x1.w *= s32;
        x2.x *= s32; x2.y *= s32; x2.z *= s32; x2.w *= s32;
        dstz = Zbf + (size_t)(256 + b) * 768;
    }
    float ss = x0.x*x0.x + x0.y*x0.y + x0.z*x0.z + x0.w*x0.w
             + x1.x*x1.x + x1.y*x1.y + x1.z*x1.z + x1.w*x1.w
             + x2.x*x2.x + x2.y*x2.y + x2.z*x2.z + x2.w*x2.w;
    #pragma unroll
    for (int off = 32; off > 0; off >>= 1) ss += __shfl_xor(ss, off);
    float sc = 1.0f / fmaxf(sqrtf(ss), 1e-12f);
    x0.x *= sc; x0.y *= sc; x0.z *= sc; x0.w *= sc;
    x1.x *= sc; x1.y *= sc; x1.z *= sc; x1.w *= sc;
    x2.x *= sc; x2.y *= sc; x2.z *= sc; x2.w *= sc;
    if (isfp8) {
        uint32_t* d32 = (uint32_t*)dst8;
        d32[ln] = pk_fp8(x0); d32[ln + 64] = pk_fp8(x1); d32[ln + 128] = pk_fp8(x2);
    } else {
        us4 u0, u1, u2;
        u0.x = f2bf(x0.x); u0.y = f2bf(x0.y); u0.z = f2bf(x0.z); u0.w = f2bf(x0.w);
        u1.x = f2bf(x1.x); u1.y = f2bf(x1.y); u1.z = f2bf(x1.z); u1.w = f2bf(x1.w);
        u2.x = f2bf(x2.x); u2.y = f2bf(x2.y); u2.z = f2bf(x2.z); u2.w = f2bf(x2.w);
        us4* d4 = (us4*)dstz;
        d4[ln] = u0; d4[ln + 64] = u1; d4[ln + 128] = u2;
    }
}

// ---------- FUSED kernel: blocks [0,9) = Gram (first); [9,2057) = MX-FP8 GEMM + DTW ----
// GEMM (this round's change): ISSUE-EARLY staging. Per iter:
//   sync1 (drains stage(k) vmcnt) -> read av+bv fragments to REGISTERS ->
//   sync2 (lgkm-drained barrier: all waves' LDS reads done) -> STAGE(k+1)
//   (single 32 KB buffer now safe to overwrite) -> sched_barrier -> 16 MFMA on regs.
// stage(k+1) has the MFMA cluster (~600-1000 cyc) to land before next sync1 ->
// L2 latency leaves the critical path (only the prologue pays it once).
// Cost: 64 fragment VGPRs held across sync2 -> ~150 regs -> 3 blocks/CU
// (__launch_bounds__(256,3)); R7/R8 showed this GEMM is occupancy-insensitive 19-37%.
// DTW: exp-domain DP (R18-proven, E0=-40 range-verified).
__global__ __launch_bounds__(256, 3) void k_fused(
    const uint8_t* __restrict__ A, const uint8_t* __restrict__ B,
    const ushort_t* __restrict__ Z,
    float* __restrict__ G, float* __restrict__ P, float* __restrict__ Dm)
{
    __shared__ __align__(16) ushort_t lds[16384];   // 32 KB
    const int t = threadIdx.x;
    const int lane = t & 63, w = t >> 6;
    const int lr = lane & 15, lk = lane >> 4;

    if (blockIdx.x < 9) {
        // ---------------- Gram path (bf16): G = 10 * Z @ Z^T + per-row exp-sums ----------
        ushort_t* As = lds;
        ushort_t* Bs = lds + 8192;
        const int bx = blockIdx.x;
        const int m0 = (bx / 3) * 128, n0 = (bx % 3) * 128;
        const int wr = w >> 1, wc = w & 1;
        f32x4 acc[4][4] = {};
        for (int k0 = 0; k0 < 768; k0 += 64) {
            #pragma unroll
            for (int ii = 0; ii < 4; ++ii) {
                int idx = ii * 256 + t;
                int row = idx >> 3, kc = (idx & 7) * 8;
                __builtin_amdgcn_global_load_lds(
                    (const GLB_AS void*)(Z + (size_t)(m0 + row) * 768 + (k0 + kc)),
                    (LDS_AS void*)(As + idx * 8), 16, 0, 0);
            }
            #pragma unroll
            for (int ii = 0; ii < 4; ++ii) {
                int idx = ii * 256 + t;
                int row = idx >> 3, kc = (idx & 7) * 8;
                __builtin_amdgcn_global_load_lds(
                    (const GLB_AS void*)(Z + (size_t)(n0 + row) * 768 + (k0 + kc)),
                    (LDS_AS void*)(Bs + idx * 8), 16, 0, 0);
            }
            __syncthreads();
            #pragma unroll
            for (int kk = 0; kk < 2; ++kk) {
                short8 av[4], bv[4];
                #pragma unroll
                for (int f = 0; f < 4; ++f)
                    av[f] = *(const short8*)(As + (wr * 64 + f * 16 + lr) * 64 + kk * 32 + lk * 8);
                #pragma unroll
                for (int f = 0; f < 4; ++f)
                    bv[f] = *(const short8*)(Bs + (wc * 64 + f * 16 + lr) * 64 + kk * 32 + lk * 8);
                #pragma unroll
                for (int fr = 0; fr < 4; ++fr)
                    #pragma unroll
                    for (int fc = 0; fc < 4; ++fc)
                        acc[fr][fc] = __builtin_amdgcn_mfma_f32_16x16x32_bf16(av[fr], bv[fc], acc[fr][fc], 0, 0, 0);
            }
            __syncthreads();
        }
        #pragma unroll
        for (int fr = 0; fr < 4; ++fr)
            #pragma unroll
            for (int fc = 0; fc < 4; ++fc) {
                int col = n0 + wc * 64 + fc * 16 + lr;
                #pragma unroll
                for (int q = 0; q < 4; ++q) {
                    int row = m0 + wr * 64 + fr * 16 + lk * 4 + q;
                    G[(size_t)row * 384 + col] = 10.0f * acc[fr][fc][q];
                }
            }
        #pragma unroll
        for (int fr = 0; fr < 4; ++fr)
            #pragma unroll
            for (int q = 0; q < 4; ++q) {
                float e = 0.0f;
                #pragma unroll
                for (int fc = 0; fc < 4; ++fc)
                    e += expf(10.0f * acc[fr][fc][q] - 10.0f);
                #pragma unroll
                for (int off = 1; off < 16; off <<= 1) e += __shfl_xor(e, off);
                if (lr == 0) {
                    int row = m0 + wr * 64 + fr * 16 + lk * 4 + q;
                    atomicAdd(&P[row * 3 + (bx % 3)], e);
                }
            }
        return;
    }

    // ---------------- MX-FP8 GEMM + DTW path ----------------
    uint8_t* lds8 = (uint8_t*)lds;                  // A tile at 0, B tile at 16384
    const int wr = w >> 1, wc = w & 1;
    const int sw = lr & 7;                          // row-derived 3-bit swizzle (row&7 == lr&7)
    // L2-locality map: XCD owns m-tiles [xcd*8, xcd*8+8); groups of 8 consecutive
    // blocks within the XCD share one n-tile.
    const int lin = blockIdx.x - 9;
    const int xcd = lin & 7, idx = lin >> 3;
    const int ntl = idx >> 3;
    const int mt  = xcd * 8 + (idx & 7);
    const int m0 = mt * 128, n0 = ntl * 128;

    f32x4 acc[4][4] = {};

#define STAGE(tile) { \
    _Pragma("unroll") \
    for (int i_ = 0; i_ < 4; ++i_) { \
        int s_ = i_ * 256 + t, row_ = s_ >> 3, c16_ = s_ & 7; \
        int g_ = (c16_ ^ (row_ & 7)) * 16; \
        __builtin_amdgcn_global_load_lds( \
            (const GLB_AS void*)(A + (size_t)(m0 + row_) * 768 + (tile) * 128 + g_), \
            (LDS_AS void*)(lds8 + s_ * 16), 16, 0, 0); \
        __builtin_amdgcn_global_load_lds( \
            (const GLB_AS void*)(B + (size_t)(n0 + row_) * 768 + (tile) * 128 + g_), \
            (LDS_AS void*)(lds8 + 16384 + s_ * 16), 16, 0, 0); \
    } }

    STAGE(0)
    #pragma unroll 1
    for (int k0 = 0; k0 < 6; ++k0) {
        __syncthreads();                 // sync1: stage(k0) resident (drains vmcnt)
        // fragment reads -> registers (lane: row wr/wc*64+f*16+lr, granules lk*2,lk*2+1)
        i32x8 av[4], bv[4];
        #pragma unroll
        for (int f = 0; f < 4; ++f) {
            const uint8_t* ra = lds8 + (wr * 64 + f * 16 + lr) * 128;
            i32x4 alo = *(const i32x4*)(ra + (((lk * 2) ^ sw) * 16));
            i32x4 ahi = *(const i32x4*)(ra + (((lk * 2 + 1) ^ sw) * 16));
            av[f][0] = alo[0]; av[f][1] = alo[1]; av[f][2] = alo[2]; av[f][3] = alo[3];
            av[f][4] = ahi[0]; av[f][5] = ahi[1]; av[f][6] = ahi[2]; av[f][7] = ahi[3];
            const uint8_t* rb = lds8 + 16384 + (wc * 64 + f * 16 + lr) * 128;
            i32x4 blo = *(const i32x4*)(rb + (((lk * 2) ^ sw) * 16));
            i32x4 bhi = *(const i32x4*)(rb + (((lk * 2 + 1) ^ sw) * 16));
            bv[f][0] = blo[0]; bv[f][1] = blo[1]; bv[f][2] = blo[2]; bv[f][3] = blo[3];
            bv[f][4] = bhi[0]; bv[f][5] = bhi[1]; bv[f][6] = bhi[2]; bv[f][7] = bhi[3];
        }
        __syncthreads();                 // sync2: ALL waves' LDS reads complete
        if (k0 < 5) STAGE(k0 + 1)        // overwrite is now safe; latency hides under MFMA
        __builtin_amdgcn_sched_barrier(0);
        #pragma unroll
        for (int fc = 0; fc < 4; ++fc)
            #pragma unroll
            for (int fr = 0; fr < 4; ++fr)
                acc[fr][fc] = __builtin_amdgcn_mfma_scale_f32_16x16x128_f8f6f4(
                    av[fr], bv[fc], acc[fr][fc], 0, 0,
                    0, 0x7F7F7F7F, 0, 0x7F7F7F7F);   // fp8/fp8, scales = 1.0
    }
#undef STAGE

    // ---- acc (sim) -> phi-domain cost Ec = exp2(K10*sim - K10/3), bf16 in wave tile ----
    // Safe without extra barrier: all waves' LDS reads of tile 5 completed at sync2(5).
    const float K10   = 14.4269504f;       // 10*log2(e)
    const float K10_3 = 4.80898347f;       // K10/3
    ushort_t* qd = lds + w * 4096;         // [64 rows][64 cols], stride 64
    #pragma unroll
    for (int fr = 0; fr < 4; ++fr)
        #pragma unroll
        for (int fc = 0; fc < 4; ++fc)
            #pragma unroll
            for (int q = 0; q < 4; ++q)
                qd[(fr * 16 + lk * 4 + q) * 64 + fc * 16 + lr] =
                    f2bf(__builtin_amdgcn_exp2f(fmaf(K10, acc[fr][fc][q], -K10_3)));
    // wave-private region: compiler orders ds_write->ds_read via lgkmcnt

    // ---- soft-DTW, phi-domain: phi_r = Ec * (phi_up + phi_left + KD*phi_diag) ----
    // E0 = -40 (peak exponent at (31,31) ~ 96 < 127; terminal ~ -19 > -126)
    const float KD   = 785.76917f;         // 2^((2/3)*K10)
    const float DG0  = 1.472968e-18f;      // 2^(E0 - (4/3)*K10)
    const float FEXT = 864.08889f;         // E0 + 94*(2/3)*K10
    const int j = lane & 31, pr = lane >> 5;
    const bool isj0 = (j == 0);
    float rp = 0.0f, rp2 = 0.0f, dgj0 = DG0;

    #pragma unroll 5
    for (int s = 0; s < 95; ++s) {
        float lf  = dpp_shr1z(rp);          // left  = lane j-1's phi (prev step)
        float dgv = dpp_shr1z(rp2);         // diag  = lane j-1's phi (two steps back)
        if (isj0) { lf = 0.0f; dgv = dgj0; }
        int ii = s - j;
        int iic = ii < 0 ? 0 : (ii > 63 ? 63 : ii);
        float Ec = bf2f(qd[iic * 64 + lane]);
        float sum = rp + lf;                // up = own rp
        sum = fmaf(KD, dgv, sum);
        float r = Ec * sum;
        bool act = (unsigned)ii < 64u;
        rp2 = act ? rp : rp2;
        rp  = act ? r  : rp;
        dgj0 = 0.0f;
    }
    if (j == 31) {   // lanes 31 (pr=0) and 63 (pr=1) hold phi(63,31)
        int b  = mt * 2 + wr;                 // video batch
        int bp = ntl * 4 + wc * 2 + pr;       // text batch
        Dm[(size_t)b * 128 + bp] = (FEXT - __builtin_amdgcn_logf(rp)) * (1.0f / K10);
    }
}

// ---------- per-row losses: one WAVE per row i (lane-parallel reductions) ----------
__global__ __launch_bounds__(256) void k_rowloss(
    const float* __restrict__ G, const float* __restrict__ P,
    const float* __restrict__ Dm, float* __restrict__ rowloss)
{
    const int w = threadIdx.x >> 6, ln = threadIdx.x & 63;
    const int i = blockIdx.x * 4 + w;
    float d1 = G[(size_t)i * 384 + 128 + i];
    float d3 = G[(size_t)i * 384 + 256 + i];
    float d4 = G[(size_t)(128 + i) * 384 + 256 + i];
    float l1 = 0.5f * ((10.0f + logf(P[i * 3 + 1]) - d1) + (10.0f + logf(P[(128 + i) * 3 + 0]) - d1));
    float l3 = 0.5f * ((10.0f + logf(P[i * 3 + 2]) - d3) + (10.0f + logf(P[(256 + i) * 3 + 0]) - d3));
    float l4 = 0.5f * ((10.0f + logf(P[(128 + i) * 3 + 2]) - d4) + (10.0f + logf(P[(256 + i) * 3 + 1]) - d4));
    float ntr = P[i * 3 + 0] + P[i * 3 + 1] - expf(G[(size_t)i * 384 + i] - 10.0f);
    float ntc = P[(128 + i) * 3 + 0] + P[(128 + i) * 3 + 1]
              - expf(G[(size_t)(128 + i) * 384 + 128 + i] - 10.0f);
    float nt = 0.5f * (10.0f + logf(ntr) - d1) + 0.5f * (10.0f + logf(ntc) - d1);
    // DTW CE: row i of logits (-10*Dm[i][*]) and column i (-10*Dm[*][i])
    float v0 = -10.0f * Dm[i * 128 + ln],        v1 = -10.0f * Dm[i * 128 + 64 + ln];
    float c0 = -10.0f * Dm[ln * 128 + i],        c1 = -10.0f * Dm[(64 + ln) * 128 + i];
    float mxr = fmaxf(v0, v1), mxc = fmaxf(c0, c1);
    #pragma unroll
    for (int off = 32; off > 0; off >>= 1) {
        mxr = fmaxf(mxr, __shfl_xor(mxr, off));
        mxc = fmaxf(mxc, __shfl_xor(mxc, off));
    }
    float sr = expf(v0 - mxr) + expf(v1 - mxr);
    float sc = expf(c0 - mxc) + expf(c1 - mxc);
    #pragma unroll
    for (int off = 32; off > 0; off >>= 1) {
        sr += __shfl_xor(sr, off);
        sc += __shfl_xor(sc, off);
    }
    float dd = -10.0f * Dm[i * 128 + i];
    float ld = 0.5f * ((mxr + logf(sr) - dd) + (mxc + logf(sc) - dd));
    if (ln == 0) rowloss[i] = l1 + l3 + l4 + nt + 0.1f * ld;
}

// ---------- final sum ----------
__global__ __launch_bounds__(128) void k_sum(const float* __restrict__ rowloss, float* __restrict__ out)
{
    int i = threadIdx.x;
    float tot = rowloss[i];
    #pragma unroll
    for (int o = 32; o > 0; o >>= 1) tot += __shfl_down(tot, o);
    __shared__ float sm[2];
    if ((i & 63) == 0) sm[i >> 6] = tot;
    __syncthreads();
    if (i == 0) out[0] = (sm[0] + sm[1]) / (128.0f * 5.0f);
}

extern "C" void kernel_launch(void* const* d_in, const int* in_sizes, int n_in,
                              void* d_out, int out_size, void* d_ws, size_t ws_size,
                              hipStream_t stream)
{
    (void)in_sizes; (void)n_in; (void)out_size; (void)ws_size;
    const float* video = (const float*)d_in[0];   // [128,768]
    const float* sent  = (const float*)d_in[1];   // [128,768]
    const float* cand  = (const float*)d_in[2];   // [128,32,768]
    const float* frame = (const float*)d_in[3];   // [128,64,768]
    // d_in[4] = pos_step: unused by the reference.

    char* ws = (char*)d_ws;
    size_t off = 0;
    auto alloc = [&](size_t b) { void* p = ws + off; off = (off + b + 255) & ~(size_t)255; return p; };
    uint8_t*  A8  = (uint8_t*)alloc((size_t)8192 * 768);
    uint8_t*  B8  = (uint8_t*)alloc((size_t)4096 * 768);
    ushort_t* Zbf = (ushort_t*)alloc((size_t)384 * 768 * 2);
    float*    G   = (float*)alloc((size_t)384 * 384 * 4);
    float*    P   = (float*)alloc((size_t)1152 * 4);
    float*    Dm  = (float*)alloc((size_t)128 * 128 * 4);
    float*    RL  = (float*)alloc((size_t)128 * 4);

    k_prep_all <<<3168, 256, 0, stream>>>(frame, cand, video, sent, A8, B8, Zbf, P);
    k_fused    <<<2057, 256, 0, stream>>>(A8, B8, Zbf, G, P, Dm);
    k_rowloss  <<<32, 256, 0, stream>>>(G, P, Dm, RL);
    k_sum      <<<1, 128, 0, stream>>>(RL, (float*)d_out);
}

// Round 20
// 72.427 us; speedup vs baseline: 1.0299x; 1.0299x over previous
//
#include <hip/hip_runtime.h>
#include <stdint.h>

typedef unsigned short ushort_t;
typedef __attribute__((ext_vector_type(4))) float f32x4;
typedef __attribute__((ext_vector_type(8))) short short8;
typedef __attribute__((ext_vector_type(4))) ushort_t us4;
typedef __attribute__((ext_vector_type(4))) int i32x4;
typedef __attribute__((ext_vector_type(8))) int i32x8;

#define LDS_AS __attribute__((address_space(3)))
#define GLB_AS __attribute__((address_space(1)))

__device__ __forceinline__ ushort_t f2bf(float f) {
    uint32_t u = __float_as_uint(f);
    u += 0x7FFFu + ((u >> 16) & 1u);   // RNE
    return (ushort_t)(u >> 16);
}

__device__ __forceinline__ float bf2f(ushort_t u) {
    return __uint_as_float(((uint32_t)u) << 16);
}

__device__ __forceinline__ float dpp_shr1z(float x) {   // lane l <- lane l-1; lane 0 <- 0.0
    return __int_as_float(__builtin_amdgcn_update_dpp(
        0, __float_as_int(x), 0x138, 0xF, 0xF, false));  // wave_shr:1
}

// pack float4 -> 4 x fp8 e4m3 (OCP) in one uint32
__device__ __forceinline__ uint32_t pk_fp8(float4 x) {
    int u = __builtin_amdgcn_cvt_pk_fp8_f32(x.x, x.y, 0, false);   // bytes 0,1
    u = __builtin_amdgcn_cvt_pk_fp8_f32(x.z, x.w, u, true);        // bytes 2,3
    return (uint32_t)u;
}

// ---------- prep: row-normalize; frame/cand -> FP8 (A/B), video/sent/mean -> BF16 (Z) ----
__global__ __launch_bounds__(256) void k_prep_all(
    const float* __restrict__ frame, const float* __restrict__ cand,
    const float* __restrict__ video, const float* __restrict__ sent,
    uint8_t* __restrict__ A8, uint8_t* __restrict__ B8, ushort_t* __restrict__ Zbf,
    float* __restrict__ P)
{
    if (blockIdx.x == 0) {
        for (int i = threadIdx.x; i < 1152; i += 256) P[i] = 0.0f;
    }
    const int w = threadIdx.x >> 6, ln = threadIdx.x & 63;
    const int r = blockIdx.x * 4 + w;
    float4 x0, x1, x2;
    bool isfp8 = (r < 12288);
    uint8_t* dst8 = nullptr;
    ushort_t* dstz = nullptr;
    if (r < 8192) {
        const float4* s = (const float4*)(frame + (size_t)r * 768);
        x0 = s[ln]; x1 = s[ln + 64]; x2 = s[ln + 128];
        dst8 = A8 + (size_t)r * 768;
    } else if (r < 12288) {
        int q = r - 8192;
        const float4* s = (const float4*)(cand + (size_t)q * 768);
        x0 = s[ln]; x1 = s[ln + 64]; x2 = s[ln + 128];
        dst8 = B8 + (size_t)q * 768;
    } else if (r < 12416) {
        int q = r - 12288;
        const float4* s = (const float4*)(video + (size_t)q * 768);
        x0 = s[ln]; x1 = s[ln + 64]; x2 = s[ln + 128];
        dstz = Zbf + (size_t)q * 768;
    } else if (r < 12544) {
        int q = r - 12416;
        const float4* s = (const float4*)(sent + (size_t)q * 768);
        x0 = s[ln]; x1 = s[ln + 64]; x2 = s[ln + 128];
        dstz = Zbf + (size_t)(128 + q) * 768;
    } else {
        int b = r - 12544;
        x0 = x1 = x2 = make_float4(0.f, 0.f, 0.f, 0.f);
        for (int k = 0; k < 32; ++k) {
            const float4* s = (const float4*)(cand + (size_t)(b * 32 + k) * 768);
            float4 y0 = s[ln], y1 = s[ln + 64], y2 = s[ln + 128];
            x0.x += y0.x; x0.y += y0.y; x0.z += y0.z; x0.w += y0.w;
            x1.x += y1.x; x1.y += y1.y; x1.z += y1.z; x1.w += y1.w;
            x2.x += y2.x; x2.y += y2.y; x2.z += y2.z; x2.w += y2.w;
        }
        const float s32 = 1.0f / 32.0f;
        x0.x *= s32; x0.y *= s32; x0.z *= s32; x0.w *= s32;
        x1.x *= s32; x1.y *= s32; x1.z *= s32; x1.w *= s32;
        x2.x *= s32; x2.y *= s32; x2.z *= s32; x2.w *= s32;
        dstz = Zbf + (size_t)(256 + b) * 768;
    }
    float ss = x0.x*x0.x + x0.y*x0.y + x0.z*x0.z + x0.w*x0.w
             + x1.x*x1.x + x1.y*x1.y + x1.z*x1.z + x1.w*x1.w
             + x2.x*x2.x + x2.y*x2.y + x2.z*x2.z + x2.w*x2.w;
    #pragma unroll
    for (int off = 32; off > 0; off >>= 1) ss += __shfl_xor(ss, off);
    float sc = 1.0f / fmaxf(sqrtf(ss), 1e-12f);
    x0.x *= sc; x0.y *= sc; x0.z *= sc; x0.w *= sc;
    x1.x *= sc; x1.y *= sc; x1.z *= sc; x1.w *= sc;
    x2.x *= sc; x2.y *= sc; x2.z *= sc; x2.w *= sc;
    if (isfp8) {
        uint32_t* d32 = (uint32_t*)dst8;
        d32[ln] = pk_fp8(x0); d32[ln + 64] = pk_fp8(x1); d32[ln + 128] = pk_fp8(x2);
    } else {
        us4 u0, u1, u2;
        u0.x = f2bf(x0.x); u0.y = f2bf(x0.y); u0.z = f2bf(x0.z); u0.w = f2bf(x0.w);
        u1.x = f2bf(x1.x); u1.y = f2bf(x1.y); u1.z = f2bf(x1.z); u1.w = f2bf(x1.w);
        u2.x = f2bf(x2.x); u2.y = f2bf(x2.y); u2.z = f2bf(x2.z); u2.w = f2bf(x2.w);
        us4* d4 = (us4*)dstz;
        d4[ln] = u0; d4[ln + 64] = u1; d4[ln + 128] = u2;
    }
}

// ---------- FUSED kernel: blocks [0,9) = Gram (first); [9,2057) = MX-FP8 GEMM + DTW ----
// DTW: exponential-domain DP. phi = 2^(E0 + kappa*(i+j) - Rhat), kappa = (2/3)*K10 ->
// phi_r = Ec * (phi_left + phi_up + KD*phi_diag), ZERO transcendentals per step
// (Ec = exp2(K10*sim - K10/3) precomputed in the epilogue, bf16 in qd).
// RANGE: exponent PEAKS at the square corner (31,31): E0 + 134.6 +- 3 -> E0 = -40
// puts the peak at ~96 (<127, 10-sigma safe). Terminal (63,31): ~ -19 +- 10 (>-126).
// Off-corridor cells underflow to 0 gracefully. Boundary inf -> phi=0 (dpp injects 0);
// start cell via DG0 = 2^(E0-(4/3)K10). Final: D = (E0 + 94*(2/3)K10 - log2 phi)/K10.
__global__ __launch_bounds__(256, 4) void k_fused(
    const uint8_t* __restrict__ A, const uint8_t* __restrict__ B,
    const ushort_t* __restrict__ Z,
    float* __restrict__ G, float* __restrict__ P, float* __restrict__ Dm)
{
    __shared__ __align__(16) ushort_t lds[16384];   // 32 KB
    const int t = threadIdx.x;
    const int lane = t & 63, w = t >> 6;
    const int lr = lane & 15, lk = lane >> 4;

    if (blockIdx.x < 9) {
        // ---------------- Gram path (bf16): G = 10 * Z @ Z^T + per-row exp-sums ----------
        ushort_t* As = lds;
        ushort_t* Bs = lds + 8192;
        const int bx = blockIdx.x;
        const int m0 = (bx / 3) * 128, n0 = (bx % 3) * 128;
        const int wr = w >> 1, wc = w & 1;
        f32x4 acc[4][4] = {};
        for (int k0 = 0; k0 < 768; k0 += 64) {
            #pragma unroll
            for (int ii = 0; ii < 4; ++ii) {
                int idx = ii * 256 + t;
                int row = idx >> 3, kc = (idx & 7) * 8;
                __builtin_amdgcn_global_load_lds(
                    (const GLB_AS void*)(Z + (size_t)(m0 + row) * 768 + (k0 + kc)),
                    (LDS_AS void*)(As + idx * 8), 16, 0, 0);
            }
            #pragma unroll
            for (int ii = 0; ii < 4; ++ii) {
                int idx = ii * 256 + t;
                int row = idx >> 3, kc = (idx & 7) * 8;
                __builtin_amdgcn_global_load_lds(
                    (const GLB_AS void*)(Z + (size_t)(n0 + row) * 768 + (k0 + kc)),
                    (LDS_AS void*)(Bs + idx * 8), 16, 0, 0);
            }
            __syncthreads();
            #pragma unroll
            for (int kk = 0; kk < 2; ++kk) {
                short8 av[4], bv[4];
                #pragma unroll
                for (int f = 0; f < 4; ++f)
                    av[f] = *(const short8*)(As + (wr * 64 + f * 16 + lr) * 64 + kk * 32 + lk * 8);
                #pragma unroll
                for (int f = 0; f < 4; ++f)
                    bv[f] = *(const short8*)(Bs + (wc * 64 + f * 16 + lr) * 64 + kk * 32 + lk * 8);
                #pragma unroll
                for (int fr = 0; fr < 4; ++fr)
                    #pragma unroll
                    for (int fc = 0; fc < 4; ++fc)
                        acc[fr][fc] = __builtin_amdgcn_mfma_f32_16x16x32_bf16(av[fr], bv[fc], acc[fr][fc], 0, 0, 0);
            }
            __syncthreads();
        }
        #pragma unroll
        for (int fr = 0; fr < 4; ++fr)
            #pragma unroll
            for (int fc = 0; fc < 4; ++fc) {
                int col = n0 + wc * 64 + fc * 16 + lr;
                #pragma unroll
                for (int q = 0; q < 4; ++q) {
                    int row = m0 + wr * 64 + fr * 16 + lk * 4 + q;
                    G[(size_t)row * 384 + col] = 10.0f * acc[fr][fc][q];
                }
            }
        #pragma unroll
        for (int fr = 0; fr < 4; ++fr)
            #pragma unroll
            for (int q = 0; q < 4; ++q) {
                float e = 0.0f;
                #pragma unroll
                for (int fc = 0; fc < 4; ++fc)
                    e += expf(10.0f * acc[fr][fc][q] - 10.0f);
                #pragma unroll
                for (int off = 1; off < 16; off <<= 1) e += __shfl_xor(e, off);
                if (lr == 0) {
                    int row = m0 + wr * 64 + fr * 16 + lk * 4 + q;
                    atomicAdd(&P[row * 3 + (bx % 3)], e);
                }
            }
        return;
    }

    // ---------------- MX-FP8 GEMM + DTW path ----------------
    uint8_t* lds8 = (uint8_t*)lds;                  // A tile at 0, B tile at 16384
    const int wr = w >> 1, wc = w & 1;
    const int sw = lr & 7;                          // row-derived 3-bit swizzle (row&7 == lr&7)
    // L2-locality map: XCD owns m-tiles [xcd*8, xcd*8+8); groups of 8 consecutive
    // blocks within the XCD share one n-tile.
    const int lin = blockIdx.x - 9;
    const int xcd = lin & 7, idx = lin >> 3;
    const int ntl = idx >> 3;
    const int mt  = xcd * 8 + (idx & 7);
    const int m0 = mt * 128, n0 = ntl * 128;

    f32x4 acc[4][4] = {};

    #pragma unroll 1
    for (int k0 = 0; k0 < 6; ++k0) {
        // stage A (16 KB) + B (16 KB): slot s = row*8 + c16; source granule pre-swizzled
        #pragma unroll
        for (int i = 0; i < 4; ++i) {
            int s = i * 256 + t, row = s >> 3, c16 = s & 7;
            int g = (c16 ^ (row & 7)) * 16;
            __builtin_amdgcn_global_load_lds(
                (const GLB_AS void*)(A + (size_t)(m0 + row) * 768 + k0 * 128 + g),
                (LDS_AS void*)(lds8 + s * 16), 16, 0, 0);
            __builtin_amdgcn_global_load_lds(
                (const GLB_AS void*)(B + (size_t)(n0 + row) * 768 + k0 * 128 + g),
                (LDS_AS void*)(lds8 + 16384 + s * 16), 16, 0, 0);
        }
        __syncthreads();
        // A fragments: lane holds row (wr*64+f*16+lr), k-granules lk*2, lk*2+1 (swizzled)
        i32x8 av[4];
        #pragma unroll
        for (int f = 0; f < 4; ++f) {
            const uint8_t* rb = lds8 + (wr * 64 + f * 16 + lr) * 128;
            i32x4 lo = *(const i32x4*)(rb + (((lk * 2) ^ sw) * 16));
            i32x4 hi = *(const i32x4*)(rb + (((lk * 2 + 1) ^ sw) * 16));
            av[f][0] = lo[0]; av[f][1] = lo[1]; av[f][2] = lo[2]; av[f][3] = lo[3];
            av[f][4] = hi[0]; av[f][5] = hi[1]; av[f][6] = hi[2]; av[f][7] = hi[3];
        }
        #pragma unroll
        for (int fc = 0; fc < 4; ++fc) {
            const uint8_t* rb = lds8 + 16384 + (wc * 64 + fc * 16 + lr) * 128;
            i32x4 lo = *(const i32x4*)(rb + (((lk * 2) ^ sw) * 16));
            i32x4 hi = *(const i32x4*)(rb + (((lk * 2 + 1) ^ sw) * 16));
            i32x8 bv;
            bv[0] = lo[0]; bv[1] = lo[1]; bv[2] = lo[2]; bv[3] = lo[3];
            bv[4] = hi[0]; bv[5] = hi[1]; bv[6] = hi[2]; bv[7] = hi[3];
            #pragma unroll
            for (int fr = 0; fr < 4; ++fr)
                acc[fr][fc] = __builtin_amdgcn_mfma_scale_f32_16x16x128_f8f6f4(
                    av[fr], bv, acc[fr][fc], 0, 0,
                    0, 0x7F7F7F7F, 0, 0x7F7F7F7F);   // fp8/fp8, scales = 1.0
        }
        __syncthreads();
    }

    // ---- acc (sim) -> phi-domain cost Ec = exp2(K10*sim - K10/3), bf16 in wave tile ----
    const float K10   = 14.4269504f;       // 10*log2(e)
    const float K10_3 = 4.80898347f;       // K10/3
    ushort_t* qd = lds + w * 4096;         // [64 rows][64 cols], stride 64
    #pragma unroll
    for (int fr = 0; fr < 4; ++fr)
        #pragma unroll
        for (int fc = 0; fc < 4; ++fc)
            #pragma unroll
            for (int q = 0; q < 4; ++q)
                qd[(fr * 16 + lk * 4 + q) * 64 + fc * 16 + lr] =
                    f2bf(__builtin_amdgcn_exp2f(fmaf(K10, acc[fr][fc][q], -K10_3)));
    // wave-private region: compiler orders ds_write->ds_read via lgkmcnt

    // ---- soft-DTW, phi-domain: phi_r = Ec * (phi_up + phi_left + KD*phi_diag) ----
    // E0 = -40 (peak exponent at (31,31) ~ 96 < 127; terminal ~ -19 > -126)
    const float KD   = 785.76917f;         // 2^((2/3)*K10)
    const float DG0  = 1.472968e-18f;      // 2^(E0 - (4/3)*K10)
    const float FEXT = 864.08889f;         // E0 + 94*(2/3)*K10
    const int j = lane & 31, pr = lane >> 5;
    const bool isj0 = (j == 0);
    float rp = 0.0f, rp2 = 0.0f, dgj0 = DG0;

    #pragma unroll 5
    for (int s = 0; s < 95; ++s) {
        float lf  = dpp_shr1z(rp);          // left  = lane j-1's phi (prev step)
        float dgv = dpp_shr1z(rp2);         // diag  = lane j-1's phi (two steps back)
        if (isj0) { lf = 0.0f; dgv = dgj0; }
        int ii = s - j;
        int iic = ii < 0 ? 0 : (ii > 63 ? 63 : ii);
        float Ec = bf2f(qd[iic * 64 + lane]);
        float sum = rp + lf;                // up = own rp
        sum = fmaf(KD, dgv, sum);
        float r = Ec * sum;
        bool act = (unsigned)ii < 64u;
        rp2 = act ? rp : rp2;
        rp  = act ? r  : rp;
        dgj0 = 0.0f;
    }
    if (j == 31) {   // lanes 31 (pr=0) and 63 (pr=1) hold phi(63,31)
        int b  = mt * 2 + wr;                 // video batch
        int bp = ntl * 4 + wc * 2 + pr;       // text batch
        Dm[(size_t)b * 128 + bp] = (FEXT - __builtin_amdgcn_logf(rp)) * (1.0f / K10);
    }
}

// ---------- per-row losses: one WAVE per row i (lane-parallel reductions) ----------
__global__ __launch_bounds__(256) void k_rowloss(
    const float* __restrict__ G, const float* __restrict__ P,
    const float* __restrict__ Dm, float* __restrict__ rowloss)
{
    const int w = threadIdx.x >> 6, ln = threadIdx.x & 63;
    const int i = blockIdx.x * 4 + w;
    float d1 = G[(size_t)i * 384 + 128 + i];
    float d3 = G[(size_t)i * 384 + 256 + i];
    float d4 = G[(size_t)(128 + i) * 384 + 256 + i];
    float l1 = 0.5f * ((10.0f + logf(P[i * 3 + 1]) - d1) + (10.0f + logf(P[(128 + i) * 3 + 0]) - d1));
    float l3 = 0.5f * ((10.0f + logf(P[i * 3 + 2]) - d3) + (10.0f + logf(P[(256 + i) * 3 + 0]) - d3));
    float l4 = 0.5f * ((10.0f + logf(P[(128 + i) * 3 + 2]) - d4) + (10.0f + logf(P[(256 + i) * 3 + 1]) - d4));
    float ntr = P[i * 3 + 0] + P[i * 3 + 1] - expf(G[(size_t)i * 384 + i] - 10.0f);
    float ntc = P[(128 + i) * 3 + 0] + P[(128 + i) * 3 + 1]
              - expf(G[(size_t)(128 + i) * 384 + 128 + i] - 10.0f);
    float nt = 0.5f * (10.0f + logf(ntr) - d1) + 0.5f * (10.0f + logf(ntc) - d1);
    // DTW CE: row i of logits (-10*Dm[i][*]) and column i (-10*Dm[*][i])
    float v0 = -10.0f * Dm[i * 128 + ln],        v1 = -10.0f * Dm[i * 128 + 64 + ln];
    float c0 = -10.0f * Dm[ln * 128 + i],        c1 = -10.0f * Dm[(64 + ln) * 128 + i];
    float mxr = fmaxf(v0, v1), mxc = fmaxf(c0, c1);
    #pragma unroll
    for (int off = 32; off > 0; off >>= 1) {
        mxr = fmaxf(mxr, __shfl_xor(mxr, off));
        mxc = fmaxf(mxc, __shfl_xor(mxc, off));
    }
    float sr = expf(v0 - mxr) + expf(v1 - mxr);
    float sc = expf(c0 - mxc) + expf(c1 - mxc);
    #pragma unroll
    for (int off = 32; off > 0; off >>= 1) {
        sr += __shfl_xor(sr, off);
        sc += __shfl_xor(sc, off);
    }
    float dd = -10.0f * Dm[i * 128 + i];
    float ld = 0.5f * ((mxr + logf(sr) - dd) + (mxc + logf(sc) - dd));
    if (ln == 0) rowloss[i] = l1 + l3 + l4 + nt + 0.1f * ld;
}

// ---------- final sum ----------
__global__ __launch_bounds__(128) void k_sum(const float* __restrict__ rowloss, float* __restrict__ out)
{
    int i = threadIdx.x;
    float tot = rowloss[i];
    #pragma unroll
    for (int o = 32; o > 0; o >>= 1) tot += __shfl_down(tot, o);
    __shared__ float sm[2];
    if ((i & 63) == 0) sm[i >> 6] = tot;
    __syncthreads();
    if (i == 0) out[0] = (sm[0] + sm[1]) / (128.0f * 5.0f);
}

extern "C" void kernel_launch(void* const* d_in, const int* in_sizes, int n_in,
                              void* d_out, int out_size, void* d_ws, size_t ws_size,
                              hipStream_t stream)
{
    (void)in_sizes; (void)n_in; (void)out_size; (void)ws_size;
    const float* video = (const float*)d_in[0];   // [128,768]
    const float* sent  = (const float*)d_in[1];   // [128,768]
    const float* cand  = (const float*)d_in[2];   // [128,32,768]
    const float* frame = (const float*)d_in[3];   // [128,64,768]
    // d_in[4] = pos_step: unused by the reference.

    char* ws = (char*)d_ws;
    size_t off = 0;
    auto alloc = [&](size_t b) { void* p = ws + off; off = (off + b + 255) & ~(size_t)255; return p; };
    uint8_t*  A8  = (uint8_t*)alloc((size_t)8192 * 768);
    uint8_t*  B8  = (uint8_t*)alloc((size_t)4096 * 768);
    ushort_t* Zbf = (ushort_t*)alloc((size_t)384 * 768 * 2);
    float*    G   = (float*)alloc((size_t)384 * 384 * 4);
    float*    P   = (float*)alloc((size_t)1152 * 4);
    float*    Dm  = (float*)alloc((size_t)128 * 128 * 4);
    float*    RL  = (float*)alloc((size_t)128 * 4);

    k_prep_all <<<3168, 256, 0, stream>>>(frame, cand, video, sent, A8, B8, Zbf, P);
    k_fused    <<<2057, 256, 0, stream>>>(A8, B8, Zbf, G, P, Dm);
    k_rowloss  <<<32, 256, 0, stream>>>(G, P, Dm, RL);
    k_sum      <<<1, 128, 0, stream>>>(RL, (float*)d_out);
}